// Round 7
// baseline (13.381 us; speedup 1.0000x reference)
//
#include <hip/hip_runtime.h>
#include <math.h>

// Problem constants (from setup_inputs): bs=2, Q=256, C=16, P=20, T=256
#define BS    2
#define NQ    256
#define NCLS  16
#define NP    20
#define NT    256
#define NN    (BS * NQ)    // 512 predictions
#define FEPS  1e-6f
#define TPB   128          // targets per block
#define THREADS (TPB * 2)  // 256 threads: 2 lanes per target
#define QPL   10           // q-points per lane
#define NPK   5            // packed half2 regs per lane (2 points each)

typedef _Float16 h2 __attribute__((ext_vector_type(2)));

// Grid: NN*(NT/TPB) = 1024 blocks x 256 threads = 4096 waves (4/SIMD).
// Lane pair (z = tid&1) handles target t; lane z owns q in [10z,10z+10) held
// as 5 packed half2 registers -> each v_pk_*_f16 processes 2 distances,
// halving inner-loop issue count vs f32. Mins are exact in f16; sums,
// softmax, and direction math stay f32 (absmax budget: f16 quantization of
// ~N(0,1) coords is ~4e-3 << 5.9e-2 threshold). Pred polyline staged in LDS
// as duplicated-half2 pairs (1 uniform ds_read_b64 per p). No cross-lane ops
// inside the p-loop; the pair butterfly is bulk at the end.
__global__ __launch_bounds__(THREADS) void matcher_cost_kernel(
    const float* __restrict__ logits,   // [NN, NCLS]
    const float* __restrict__ ppoly,    // [NN, NP, 2]
    const int*   __restrict__ tlabels,  // [NT]
    const float* __restrict__ tpoly,    // [NT, NP, 2]
    float*       __restrict__ out)      // [NN, NT]
{
    const int bid   = blockIdx.x;            // 0..1023
    const int n     = bid >> 1;              // prediction index
    const int tbase = (bid & 1) * TPB;
    const int tid   = threadIdx.x;           // 0..255
    const int t     = tbase + (tid >> 1);    // target index
    const int z     = tid & 1;               // q-half

    __shared__ uint2 s_h[NP];      // .x = half2(px,px), .y = half2(py,py)
    __shared__ float s_prob[NCLS]; // exp(logit - max)
    __shared__ float s_invden;
    __shared__ float s_dir2[2];

    // issue the label load early (tiny, L2-resident)
    const int lbl = tlabels[t];

    // --- wave-0 staging: pred polyline (f16 dup-packed) + softmax pieces ---
    if (tid < NP) {
        float2 v = *reinterpret_cast<const float2*>(&ppoly[n * NP * 2 + 2 * tid]);
        h2 hx = { (_Float16)v.x, (_Float16)v.x };
        h2 hy = { (_Float16)v.y, (_Float16)v.y };
        s_h[tid] = make_uint2(__builtin_bit_cast(unsigned, hx),
                              __builtin_bit_cast(unsigned, hy));
    }
    if (tid < NCLS) {
        const float* lp = logits + n * NCLS;
        float mx = lp[0];
        #pragma unroll
        for (int c = 1; c < NCLS; ++c) mx = fmaxf(mx, lp[c]);
        s_prob[tid] = __expf(lp[tid] - mx);
    }
    if (tid == 0) {  // same wave as s_prob writers: in-order LDS per wave
        float den = 0.f;
        #pragma unroll
        for (int c = 0; c < NCLS; ++c) den += s_prob[c];
        s_invden = 1.f / den;
        float2 a = *reinterpret_cast<const float2*>(&ppoly[n * NP * 2]);
        float2 b = *reinterpret_cast<const float2*>(&ppoly[n * NP * 2 + 2 * (NP - 1)]);
        float dx = b.x - a.x, dy = b.y - a.y;
        float nrm = sqrtf(dx * dx + dy * dy) + FEPS;
        s_dir2[0] = dx / nrm; s_dir2[1] = dy / nrm;
    }
    __syncthreads();

    // --- per-lane target points: 5 float4 loads -> packed f16 ---
    h2 tx[NPK], ty[NPK], m2[NPK];
    float ex0, ey0, exL, eyL;   // f32 endpoints of this lane's chunk
    {
        const float* tp = &tpoly[(t * NP + z * QPL) * 2];
        #pragma unroll
        for (int j = 0; j < NPK; ++j) {
            float4 v = *reinterpret_cast<const float4*>(tp + 4 * j);
            tx[j] = (h2){ (_Float16)v.x, (_Float16)v.z };
            ty[j] = (h2){ (_Float16)v.y, (_Float16)v.w };
            m2[j] = (h2){ (_Float16)65504.f, (_Float16)65504.f };
            if (j == 0)       { ex0 = v.x; ey0 = v.y; }
            if (j == NPK - 1) { exL = v.z; eyL = v.w; }
        }
    }

    // --- polyline cost: packed-f16 inner loop, no cross-lane ops ---
    float m1f[NP];
    #pragma unroll
    for (int p = 0; p < NP; ++p) {
        const uint2 hh = s_h[p];                       // uniform ds_read_b64
        const h2 hx = __builtin_bit_cast(h2, hh.x);
        const h2 hy = __builtin_bit_cast(h2, hh.y);
        h2 dmin;
        #pragma unroll
        for (int j = 0; j < NPK; ++j) {
            h2 dx = hx - tx[j];
            dx = __builtin_elementwise_max(dx, -dx);   // |dx| (neg folds)
            h2 dy = hy - ty[j];
            dy = __builtin_elementwise_max(dy, -dy);
            h2 d = dx + dy;
            m2[j] = __builtin_elementwise_min(m2[j], d);
            dmin = (j == 0) ? d : __builtin_elementwise_min(dmin, d);
        }
        m1f[p] = fminf((float)dmin.x, (float)dmin.y);  // fold halves -> f32
    }

    // --- bulk pair butterfly + sums (f32) ---
    float sum1 = 0.f;
    #pragma unroll
    for (int p = 0; p < NP; ++p) {
        float v = m1f[p];
        v = fminf(v, __shfl_xor(v, 1, 2));
        sum1 += v;
    }
    float sum2 = 0.f;
    #pragma unroll
    for (int j = 0; j < NPK; ++j)
        sum2 += (float)m2[j].x + (float)m2[j].y;
    sum2 += __shfl_xor(sum2, 1, 2);
    const float cost_poly = (sum1 + sum2) * (0.5f / (float)NP);

    // --- endpoints: even lane has q0 (ex0), odd lane has q19 (exL) ---
    const float g1x = __shfl_xor(exL, 1, 2);
    const float g1y = __shfl_xor(eyL, 1, 2);

    if (z == 0) {
        const float cost_class = -s_prob[lbl] * s_invden;

        const float gdx = g1x - ex0;
        const float gdy = g1y - ey0;
        const float gn = sqrtf(gdx * gdx + gdy * gdy) + FEPS;
        const float cost_dir = 1.f - (s_dir2[0] * gdx + s_dir2[1] * gdy) / gn;

        out[n * NT + t] = cost_class + cost_poly + cost_dir;
    }
}

extern "C" void kernel_launch(void* const* d_in, const int* in_sizes, int n_in,
                              void* d_out, int out_size, void* d_ws, size_t ws_size,
                              hipStream_t stream) {
    const float* logits  = (const float*)d_in[0];  // [2,256,16]
    const float* ppoly   = (const float*)d_in[1];  // [2,256,20,2]
    const int*   tlabels = (const int*)d_in[2];    // [256]
    const float* tpoly   = (const float*)d_in[3];  // [256,20,2]
    float*       out     = (float*)d_out;          // [2,256,256]

    matcher_cost_kernel<<<dim3(NN * (NT / TPB)), dim3(THREADS), 0, stream>>>(
        logits, ppoly, tlabels, tpoly, out);
}

// Round 8
// 12.377 us; speedup vs baseline: 1.0811x; 1.0811x over previous
//
#include <hip/hip_runtime.h>
#include <math.h>

// Problem constants (from setup_inputs): bs=2, Q=256, C=16, P=20, T=256
#define BS   2
#define NQ   256
#define NCLS 16
#define NP   20
#define NT   256
#define NN   (BS * NQ)   // 512 predictions
#define FEPS 1e-6f
#define PHALF (NP / 2)

// Empirical best across R1-R7 (12.52 us). One block per prediction n (512
// blocks), 512 threads: lane pair (2t, 2t+1) handles target t; z = tid&1 owns
// half the p-loop. Cross-lane combine via __shfl_xor(.,1) AFTER the loop.
// All other tested decompositions (4-way q-split, SGPR staging, packed f16,
// max-occupancy composite) were neutral or worse: the op sits on a fixed
// ~8.5-9 us launch/graph-replay floor with ~4 us of latency-bound execution.
__global__ __launch_bounds__(2 * NT) void matcher_cost_kernel(
    const float* __restrict__ logits,   // [NN, NCLS]
    const float* __restrict__ ppoly,    // [NN, NP, 2]
    const int*   __restrict__ tlabels,  // [NT]
    const float* __restrict__ tpoly,    // [NT, NP, 2]
    float*       __restrict__ out)      // [NN, NT]
{
    const int n   = blockIdx.x;
    const int tid = threadIdx.x;   // 0..511
    const int t   = tid >> 1;      // target 0..255
    const int z   = tid & 1;       // p-half: 0 -> p[0,10), 1 -> p[10,20)

    __shared__ float s_px[NP];
    __shared__ float s_py[NP];
    __shared__ float s_logit[NCLS];

    // Stage pred polyline (40 floats) and logits (16 floats) into LDS.
    if (tid < NP * 2) {
        float v = ppoly[n * NP * 2 + tid];
        if (tid & 1) s_py[tid >> 1] = v;
        else         s_px[tid >> 1] = v;
    }
    if (tid < NCLS) s_logit[tid] = logits[n * NCLS + tid];
    __syncthreads();

    // --- load this thread's target polyline into registers (40 floats) ---
    float tx[NP], ty[NP];
    #pragma unroll
    for (int p = 0; p < NP; p += 2) {
        float4 v = *reinterpret_cast<const float4*>(&tpoly[(t * NP + p) * 2]);
        tx[p]     = v.x;  ty[p]     = v.y;
        tx[p + 1] = v.z;  ty[p + 1] = v.w;
    }

    // --- classification cost: -softmax(logits[n])[label[t]] ---
    float mx = s_logit[0];
    #pragma unroll
    for (int c = 1; c < NCLS; ++c) mx = fmaxf(mx, s_logit[c]);
    float denom = 0.f;
    #pragma unroll
    for (int c = 0; c < NCLS; ++c) denom += __expf(s_logit[c] - mx);
    const int lbl = tlabels[t];
    const float cost_class = -__expf(s_logit[lbl] - mx) / denom;

    // --- polyline cost: bidirectional avg-of-min L1, p-loop split across z ---
    float m2[NP];
    #pragma unroll
    for (int q = 0; q < NP; ++q) m2[q] = 1e30f;

    float sum1 = 0.f;
    const int p0 = z * PHALF;
    #pragma unroll
    for (int pp = 0; pp < PHALF; ++pp) {
        const float px = s_px[p0 + pp];   // 2 distinct LDS addrs/wave: free
        const float py = s_py[p0 + pp];
        float m1 = 1e30f;
        #pragma unroll
        for (int q = 0; q < NP; ++q) {
            const float d = fabsf(px - tx[q]) + fabsf(py - ty[q]);
            m1    = fminf(m1, d);
            m2[q] = fminf(m2[q], d);
        }
        sum1 += m1;
    }
    // combine the two p-halves across the lane pair
    sum1 += __shfl_xor(sum1, 1);
    float sum2 = 0.f;
    #pragma unroll
    for (int q = 0; q < NP; ++q)
        sum2 += fminf(m2[q], __shfl_xor(m2[q], 1));

    const float cost_poly = (sum1 + sum2) * (0.5f / (float)NP);

    // --- direction cost: 1 - cos(start->end) ---
    float pdx = s_px[NP - 1] - s_px[0];
    float pdy = s_py[NP - 1] - s_py[0];
    const float pn = sqrtf(pdx * pdx + pdy * pdy) + FEPS;
    pdx /= pn; pdy /= pn;

    float gdx = tx[NP - 1] - tx[0];
    float gdy = ty[NP - 1] - ty[0];
    const float gn = sqrtf(gdx * gdx + gdy * gdy) + FEPS;
    gdx /= gn; gdy /= gn;

    const float cost_dir = 1.f - (pdx * gdx + pdy * gdy);

    if (z == 0) out[n * NT + t] = cost_class + cost_poly + cost_dir;
}

extern "C" void kernel_launch(void* const* d_in, const int* in_sizes, int n_in,
                              void* d_out, int out_size, void* d_ws, size_t ws_size,
                              hipStream_t stream) {
    const float* logits  = (const float*)d_in[0];  // [2,256,16]
    const float* ppoly   = (const float*)d_in[1];  // [2,256,20,2]
    const int*   tlabels = (const int*)d_in[2];    // [256]
    const float* tpoly   = (const float*)d_in[3];  // [256,20,2]
    float*       out     = (float*)d_out;          // [2,256,256]

    matcher_cost_kernel<<<dim3(NN), dim3(2 * NT), 0, stream>>>(
        logits, ppoly, tlabels, tpoly, out);
}